// Round 8
// baseline (9.557 us; speedup 1.0000x reference)
//
#include <hip/hip_runtime.h>
#include <math.h>

#define TB_COLS 16
#define TB_ROWS 32
#define HX 8                               // x reach of the u32 row window
#define HY 4                               // staged y halo (hot loop uses +/-2)
#define WIN_R (TB_ROWS + 2 * HY)           // 40 rows staged
#define HUGE_BEST 0x20000000

// Exact full-row scan on global memory (cold path; expected ~0.03 pixels per
// 2x512x512 random bench, or pathological inputs). First hit while expanding
// |dx| IS the row min.
__device__ __forceinline__ void row_scan(const float* __restrict__ rowp,
                                         int x, bool fg, int dy2, int& best)
{
    for (int dx = 0; dy2 + dx * dx < best; ++dx) {
        int xr = x + dx, xl = x - dx;
        bool hit = false;
        if (xr < 512) { float m = rowp[xr]; hit = fg ? (m != 1.0f) : (m == 1.0f); }
        if (xl >= 0)  { float m = rowp[xl]; hit |= (fg ? (m != 1.0f) : (m == 1.0f)); }
        if (hit) { best = min(best, dy2 + dx * dx); break; }
        if (xr >= 512 && xl < 0) break;
    }
}

// ---------------------------------------------------------------------------
// Direct exact SDF, branchless hot path.
// Block = 16x32 output tile. 40-row x 32-col mask window staged as TWO bitmask
// arrays (fg bits, bg bits; border masking folded in) -> per-row candidate
// word is ONE LDS read. Per pixel: unrolled dy in [-2..2]; nearest opposite
// column per row via ctz/clz with SENTINEL BITS (hi|1<<31, lo|1) instead of
// zero-input cndmasks -- the phantom candidate costs 961, which can never
// satisfy the certificate. Certificate: every contribution is a real
// candidate's exact distance (or phantom >= 961), and any excluded candidate
// has |dy|>=3 -> >=9 or |dx|>=9 -> >=81; hence best <= 8 proves exactness.
// best > 8 (incl. phantom-only and no-opposite-class cases) -> exact global
// fallback, which also reproduces the 1e12 sentinel. Bit-identical to the
// fp32 reference.
// ---------------------------------------------------------------------------
__global__ __launch_bounds__(256)
void sdf_direct(const float* __restrict__ mask, float* __restrict__ out)
{
    __shared__ unsigned pairs[WIN_R * 2];  // [row*2+0]=fg bits, [row*2+1]=bg bits

    const int t    = threadIdx.x;
    const int lane = t & 63;
    const int wid  = t >> 6;

    const int img = blockIdx.x >> 9;       // 512 blocks per image
    const int rem = blockIdx.x & 511;
    const int x0  = (rem >> 4) * TB_COLS;  // strip 0..31
    const int y0  = (rem & 15) * TB_ROWS;  // ychunk 0..15
    const float* maskb = mask + (size_t)img * 262144;

    unsigned valid = 0xFFFFFFFFu;          // in-image columns of the 32-col window
    if (x0 == 0)             valid &= 0xFFFFFF00u;
    if (x0 == 512 - TB_COLS) valid &= 0x00FFFFFFu;

    // ---- stage 40 rows: 5 rounds x (4 waves x 2 rows per ballot) ----
#pragma unroll
    for (int kk = 0; kk < 5; ++kk) {
        int rrA = kk * 8 + 2 * wid;        // row of lanes 0..31 this round
        int rr  = rrA + (lane >> 5);       // this lane's row
        int gy  = y0 - HY + rr;
        int xw  = x0 - HX + (lane & 31);
        bool bit = false;
        if ((unsigned)gy < 512u && (unsigned)xw < 512u)
            bit = (maskb[(size_t)gy * 512 + xw] == 1.0f);
        unsigned long long bl = __ballot(bit);   // lo32: row rrA, hi32: row rrA+1
        if (lane < 4) {
            int r2 = rrA + (lane >> 1);
            unsigned fgw = (lane >> 1) ? (unsigned)(bl >> 32) : (unsigned)bl;
            int gy2 = y0 - HY + r2;
            unsigned vm = ((unsigned)gy2 < 512u) ? valid : 0u;
            pairs[r2 * 2 + (lane & 1)] = (lane & 1) ? (~fgw & vm) : fgw;
        }
    }
    __syncthreads();

    const int c   = t & 15;                // column within tile
    const int rg  = t >> 4;                // 0..15
    const int px  = HX + c;                // pixel's bit position (8..23)
    const int shl = 31 - px;
    const int gx  = x0 + c;

#pragma unroll
    for (int k = 0; k < 2; ++k) {
        const int ycl  = rg + k * 16;      // tile row 0..31
        const int yloc = ycl + HY;         // window row 4..35
        const int gy   = y0 + ycl;
        const bool fg  = (pairs[yloc * 2] >> px) & 1;
        const unsigned* sel = &pairs[fg ? 1 : 0];   // opposite-class bit rows

        int best = HUGE_BEST;
#pragma unroll
        for (int dy = -2; dy <= 2; ++dy) { // branchless: 5 rows, no early exit
            unsigned cnd = sel[(yloc + dy) * 2];
            unsigned hi  = (cnd >> px) | 0x80000000u;  // sentinel: phantom d=31
            unsigned lo  = (cnd << shl) | 1u;          // sentinel: phantom d=31
            unsigned d   = min((unsigned)__builtin_ctz(hi),
                               (unsigned)__builtin_clz(lo));
            best = min(best, dy * dy + (int)(d * d));
        }

        if (__builtin_expect(best > 8, 0)) {
            // cold exact fallback: recompute from scratch on global memory
            best = HUGE_BEST;
            row_scan(maskb + (size_t)gy * 512, gx, fg, 0, best);
            for (int dy = 1; dy < 512 && dy * dy < best; ++dy) {
                int yu = gy + dy, yd = gy - dy;
                if (yu < 512) row_scan(maskb + (size_t)yu * 512, gx, fg, dy * dy, best);
                if (yd >= 0)  row_scan(maskb + (size_t)yd * 512, gx, fg, dy * dy, best);
            }
        }

        // no-opposite-class sentinel: reference yields exactly sqrt(1e12)
        float fb   = (best >= HUGE_BEST) ? 1e12f : (float)best;
        float dist = sqrtf(fb);
        out[((size_t)img * 512 + gy) * 512 + gx] = fg ? -dist : dist;
    }
}

extern "C" void kernel_launch(void* const* d_in, const int* in_sizes, int n_in,
                              void* d_out, int out_size, void* d_ws, size_t ws_size,
                              hipStream_t stream) {
    const float* mask = (const float*)d_in[0];
    float* out = (float*)d_out;
    const int total = in_sizes[0];         // B*512*512
    const int nblk  = (total >> 18) << 9;  // B * 512 blocks (16x32 tiles)

    sdf_direct<<<nblk, 256, 0, stream>>>(mask, out);
}